// Round 13
// baseline (305.946 us; speedup 1.0000x reference)
//
#include <hip/hip_runtime.h>

// SingleScaleSA: B=4, N=16384, S=2048, K=32, mlp 64 -> 64 -> 128, radius 0.2.
// Round 35: base = r34 (305.4 us). ONE change: L2 single-phase.
//  - full W2 (16 KB) staged once; each wave gathers its 32 rows' full 128 B
//    in ONE 8-load burst (wave-local, no barrier) and runs all 64 k of FMA
//    uninterrupted. Zero mid-kernel barriers (was 2 barrier pairs + 2 gather
//    exposures). LDS ~51.5 KB -> 3 blocks/CU; per-wave stall collapses to a
//    single exposure against ~5000 cyc of unbroken compute.
//  - FMA order k-ascending, staging formulas identical -> numerics unchanged.
// Ball/P1/L3/final byte-identical to r34.
constexpr int kNB      = 4;
constexpr int kNPts    = 16384;
constexpr int kNS      = 2048;
constexpr int kNK      = 32;
constexpr int kC3      = 128;
constexpr int kNRows   = kNB * kNS * kNK;   // 262144
constexpr int kNGrp    = kNB * kNS;         // 8192
constexpr int kNPtsTot = kNB * kNPts;       // 65536
constexpr double kR2   = 0.2 * 0.2;

// ---------------------------------------------------------------- P1 GEMM (+prep)
__global__ __launch_bounds__(256) void ssaP1Kernel(
    const float4* points, const float* w1,
    const float* xyz, const float* newXyz, const float* w2, const float* w3,
    float* outHead, float4* soa, float* stats, float* wT2, float* wT3,
    float4* p1)
{
    __shared__ float xT[32 * 128];
    __shared__ float sW[64 * 64];
    int tid = static_cast<int>(threadIdx.x);
    int R0  = static_cast<int>(blockIdx.x) * 128;
    int ty  = tid >> 4;
    int tx  = tid & 15;
    int r   = tid & 127;
    int h   = tid >> 7;

    // ---- merged prep (blocks 0..255 cover all ranges)
    int t = static_cast<int>(blockIdx.x) * 256 + tid;
    if (t < kNPtsTot) {
        soa[t] = make_float4(xyz[t * 3 + 0], xyz[t * 3 + 1], xyz[t * 3 + 2], 0.0f);
    }
    if (t < kNB * kNS * 3) {
        outHead[t] = newXyz[t];
    }
    if (t < 512) {
        stats[t] = 0.0f;
    }
    if (t < 64 * 128) {
        int k = t >> 7;
        int c = t & 127;
        wT3[t] = w3[c * 64 + k];
    }
    if (t < 64 * 64) {
        int k = t >> 6;
        int c = t & 63;
        wT2[t] = w2[c * 64 + k];
    }

    for (int i = tid; i < 64 * 64; i += 256) {
        int k = i >> 6;
        int c = i & 63;
        sW[i] = w1[c * 67 + 3 + k];
    }
    __syncthreads();

    float acc[8][4];
    #pragma unroll
    for (int i = 0; i < 8; i++)
        #pragma unroll
        for (int j = 0; j < 4; j++) acc[i][j] = 0.0f;

    const float4* prow = points + static_cast<size_t>(R0 + r) * 16;

    #pragma unroll 1
    for (int ch = 0; ch < 2; ch++) {
        if (ch > 0) __syncthreads();
        for (int j = h * 4; j < h * 4 + 4; j++) {
            float4 v = prow[ch * 8 + j];
            int k = j * 4;
            xT[(k + 0) * 128 + r] = v.x;
            xT[(k + 1) * 128 + r] = v.y;
            xT[(k + 2) * 128 + r] = v.z;
            xT[(k + 3) * 128 + r] = v.w;
        }
        __syncthreads();

        int kw = ch * 32;
        for (int k = 0; k < 32; k++) {
            const float* xk = &xT[k * 128 + ty * 8];
            const float* wk = &sW[(kw + k) * 64 + tx * 4];
            float w0 = wk[0], w1v = wk[1], w2v = wk[2], w3v = wk[3];
            #pragma unroll
            for (int i = 0; i < 8; i++) {
                float xv = xk[i];
                acc[i][0] += xv * w0;
                acc[i][1] += xv * w1v;
                acc[i][2] += xv * w2v;
                acc[i][3] += xv * w3v;
            }
        }
    }

    #pragma unroll
    for (int i = 0; i < 8; i++) {
        p1[static_cast<size_t>(R0 + ty * 8 + i) * 16 + tx] =
            make_float4(acc[i][0], acc[i][1], acc[i][2], acc[i][3]);
    }
}

// ---------------------------------------------------------------- ball query + BN1 stats
__global__ __launch_bounds__(256) void ssaBallKernel(
    const float* newXyz, const float4* soa, const float* w1, const float* bias1,
    const float* p1f, int* ballIdx, float4* ballDxyz, float* stats)
{
    __shared__ int   sIdx[4][32];
    __shared__ float sDx[4][32];
    __shared__ float sDy[4][32];
    __shared__ float sDz[4][32];
    __shared__ float sStat[128];
    int tid  = static_cast<int>(threadIdx.x);
    int wv   = tid >> 6;
    int lane = tid & 63;
    int w    = static_cast<int>(blockIdx.x) * 4 + wv;
    int b    = w >> 11;
    if (tid < 128) sStat[tid] = 0.0f;
    __syncthreads();

    float qx = newXyz[w * 3 + 0];
    float qy = newXyz[w * 3 + 1];
    float qz = newXyz[w * 3 + 2];
    double qxd = static_cast<double>(qx);
    double qyd = static_cast<double>(qy);
    double qzd = static_cast<double>(qz);
    double qq  = qxd * qxd + qyd * qyd + qzd * qzd;
    const float4* sp = soa + b * kNPts;
    int*    oi = ballIdx  + static_cast<size_t>(w) * kNK;
    float4* od = ballDxyz + static_cast<size_t>(w) * kNK;

    int cnt = 0;
    int firstN = -1;
    float fdx = 0.0f, fdy = 0.0f, fdz = 0.0f;

    // batched scan: 8 chunks (512 points) per iteration; loads issued upfront.
    for (int base = 0; base < kNPts && cnt < kNK; base += 512) {
        float4 pA = sp[base +   0 + lane];
        float4 pB = sp[base +  64 + lane];
        float4 pC = sp[base + 128 + lane];
        float4 pD = sp[base + 192 + lane];
        float4 pE = sp[base + 256 + lane];
        float4 pF = sp[base + 320 + lane];
        float4 pG = sp[base + 384 + lane];
        float4 pH = sp[base + 448 + lane];
        #pragma unroll
        for (int c = 0; c < 8; c++) {
            if (cnt >= kNK) break;
            float4 p = (c == 0) ? pA : (c == 1) ? pB : (c == 2) ? pC : (c == 3) ? pD
                     : (c == 4) ? pE : (c == 5) ? pF : (c == 6) ? pG : pH;
            int cbase = base + c * 64;
            double pxd = static_cast<double>(p.x);
            double pyd = static_cast<double>(p.y);
            double pzd = static_cast<double>(p.z);
            double d2  = qq + (pxd * pxd + pyd * pyd + pzd * pzd)
                       - 2.0 * (qxd * pxd + qyd * pyd + qzd * pzd);
            bool hit   = (d2 <= kR2);
            unsigned long long m = __ballot(hit);
            int pos = cnt + __popcll(m & ((1ull << lane) - 1ull));
            if (hit && pos < kNK) {
                float dx = p.x - qx;
                float dy = p.y - qy;
                float dz = p.z - qz;
                oi[pos] = cbase + lane;
                od[pos] = make_float4(dx, dy, dz, 0.0f);
                sIdx[wv][pos] = cbase + lane;
                sDx[wv][pos] = dx;
                sDy[wv][pos] = dy;
                sDz[wv][pos] = dz;
                if (pos == 0) { firstN = cbase + lane; fdx = dx; fdy = dy; fdz = dz; }
            }
            cnt += __popcll(m);
        }
    }
    if (cnt < kNK) {
        unsigned long long hv = __ballot(firstN >= 0);
        int fi;
        float dx, dy, dz;
        if (hv != 0ull) {
            int src = __builtin_ctzll(hv);
            fi = __shfl(firstN, src);
            dx = __shfl(fdx, src);
            dy = __shfl(fdy, src);
            dz = __shfl(fdz, src);
        } else {
            float4 p = sp[kNPts - 1];
            fi = kNPts - 1;
            dx = p.x - qx;
            dy = p.y - qy;
            dz = p.z - qz;
        }
        for (int p2 = cnt + lane; p2 < kNK; p2 += 64) {
            oi[p2] = fi;
            od[p2] = make_float4(dx, dy, dz, 0.0f);
            sIdx[wv][p2] = fi;
            sDx[wv][p2] = dx;
            sDy[wv][p2] = dy;
            sDz[wv][p2] = dz;
        }
    }

    // BN1 stats: lane = channel; z1 = P1[gi,c] + dxyz.W1xyz[:,c] + b1[c].
    float wa  = w1[lane * 67 + 0];
    float wbv = w1[lane * 67 + 1];
    float wc  = w1[lane * 67 + 2];
    float bb  = bias1[lane];
    const float* pb = p1f + static_cast<size_t>(b) * kNPts * 64;
    float s = 0.0f, q = 0.0f;
    #pragma unroll 8
    for (int k2 = 0; k2 < kNK; k2++) {
        int g = sIdx[wv][k2];
        float val = pb[static_cast<size_t>(g) * 64 + lane]
                  + sDx[wv][k2] * wa + sDy[wv][k2] * wbv + sDz[wv][k2] * wc + bb;
        s += val;
        q += val * val;
    }
    atomicAdd(&sStat[lane], s);
    atomicAdd(&sStat[64 + lane], q);
    __syncthreads();
    if (tid < 128) {
        atomicAdd(&stats[tid], sStat[tid]);
    }
}

// ---------------------------------------------------------------- layer 2
// Single-phase wave-autonomous: full W2 in LDS (staged once); each wave
// gathers its 32 rows' full 128 B in one 8-load burst; 64-k FMA runs with
// zero mid-kernel barriers. relu(bn1(P1[gi] + dxyz@W1xyz + b1)) @ W2.
__global__ __launch_bounds__(256) void ssaLayer2Kernel(
    const float4* p1, const float* w1, const float* bias1,
    const float4* wT2f4, const float* bias2,
    const float* gamma1, const float* beta1, const float* statsIn,
    const int* ballIdx, const float4* ballDxyz,
    float4* z2, float* statsOut)
{
    __shared__ __align__(16) float sW[64 * 64];     // 16 KB (full W2^T)
    __shared__ __align__(16) float xT[4][64 * 32];  // 32 KB, wave-private
    __shared__ float sWx[256];
    __shared__ float sB[64];
    __shared__ float sG[64];
    __shared__ float sH[64];
    __shared__ float sStat[128];
    int tid  = static_cast<int>(threadIdx.x);
    int R0   = static_cast<int>(blockIdx.x) * 128;
    int ty   = tid >> 4;
    int tx   = tid & 15;
    int wv   = tid >> 6;
    int lane = tid & 63;
    int lty  = ty & 3;
    int lr   = lane & 31;
    int hh   = lane >> 5;

    if (tid < 64) {
        sB[tid] = bias2[tid];
        double mean = static_cast<double>(statsIn[tid]) / static_cast<double>(kNRows);
        double var  = static_cast<double>(statsIn[64 + tid]) / static_cast<double>(kNRows) - mean * mean;
        double rstd = 1.0 / sqrt(var + 1e-5);
        float g = static_cast<float>(rstd) * gamma1[tid];
        sG[tid] = g;
        sH[tid] = beta1[tid] - static_cast<float>(mean) * g;
        sWx[tid]       = w1[tid * 67 + 0];
        sWx[64 + tid]  = w1[tid * 67 + 1];
        sWx[128 + tid] = w1[tid * 67 + 2];
        sWx[192 + tid] = bias1[tid];
    }
    if (tid < 128) sStat[tid] = 0.0f;

    int grow = R0 + wv * 32 + lr;
    int gi = ballIdx[grow];
    float4 dd = ballDxyz[grow];
    int b = R0 >> 16;
    const float4* prow = p1 + (static_cast<size_t>(b) * kNPts + static_cast<size_t>(gi)) * 16;
    float dx = dd.x, dy = dd.y, dz = dd.z;
    float* xw = xT[wv];

    // full W2 -> LDS once (coalesced f4)
    float4* sWf4 = reinterpret_cast<float4*>(sW);
    #pragma unroll
    for (int q2 = 0; q2 < 4; q2++) {
        sWf4[q2 * 256 + tid] = wT2f4[q2 * 256 + tid];
    }
    __syncthreads();   // covers sW + sG/sH/sWx before staging reads

    // wave-local staging: 8 f4 per lane (2 lanes per row), single exposure
    #pragma unroll
    for (int m = 0; m < 8; m++) {
        float4 v = prow[hh * 8 + m];
        int kk = hh * 32 + m * 4;
        float z0  = v.x + dx * sWx[kk + 0] + dy * sWx[64 + kk + 0] + dz * sWx[128 + kk + 0] + sWx[192 + kk + 0];
        float z1v = v.y + dx * sWx[kk + 1] + dy * sWx[64 + kk + 1] + dz * sWx[128 + kk + 1] + sWx[192 + kk + 1];
        float z2v = v.z + dx * sWx[kk + 2] + dy * sWx[64 + kk + 2] + dz * sWx[128 + kk + 2] + sWx[192 + kk + 2];
        float z3v = v.w + dx * sWx[kk + 3] + dy * sWx[64 + kk + 3] + dz * sWx[128 + kk + 3] + sWx[192 + kk + 3];
        xw[(kk + 0) * 32 + lr] = fmaxf(z0  * sG[kk + 0] + sH[kk + 0], 0.0f);
        xw[(kk + 1) * 32 + lr] = fmaxf(z1v * sG[kk + 1] + sH[kk + 1], 0.0f);
        xw[(kk + 2) * 32 + lr] = fmaxf(z2v * sG[kk + 2] + sH[kk + 2], 0.0f);
        xw[(kk + 3) * 32 + lr] = fmaxf(z3v * sG[kk + 3] + sH[kk + 3], 0.0f);
    }

    float acc[8][4];
    #pragma unroll
    for (int i = 0; i < 8; i++)
        #pragma unroll
        for (int j = 0; j < 4; j++) acc[i][j] = sB[tx * 4 + j];

    for (int k = 0; k < 64; k++) {
        const float* xk = &xw[k * 32 + lty * 8];
        const float* wk = &sW[k * 64 + tx * 4];
        float w0 = wk[0], w1v = wk[1], w2v = wk[2], w3v = wk[3];
        #pragma unroll
        for (int i = 0; i < 8; i++) {
            float xv = xk[i];
            acc[i][0] += xv * w0;
            acc[i][1] += xv * w1v;
            acc[i][2] += xv * w2v;
            acc[i][3] += xv * w3v;
        }
    }

    float s[4] = {0.f, 0.f, 0.f, 0.f};
    float q[4] = {0.f, 0.f, 0.f, 0.f};
    #pragma unroll
    for (int i = 0; i < 8; i++) {
        int row = R0 + ty * 8 + i;
        z2[static_cast<size_t>(row) * 16 + tx] =
            make_float4(acc[i][0], acc[i][1], acc[i][2], acc[i][3]);
        #pragma unroll
        for (int j = 0; j < 4; j++) {
            s[j] += acc[i][j];
            q[j] += acc[i][j] * acc[i][j];
        }
    }
    #pragma unroll
    for (int j = 0; j < 4; j++) {
        s[j] += __shfl_xor(s[j], 16); q[j] += __shfl_xor(q[j], 16);
        s[j] += __shfl_xor(s[j], 32); q[j] += __shfl_xor(q[j], 32);
    }
    if (lane < 16) {
        #pragma unroll
        for (int j = 0; j < 4; j++) {
            atomicAdd(&sStat[tx * 4 + j],      s[j]);
            atomicAdd(&sStat[64 + tx * 4 + j], q[j]);
        }
    }
    __syncthreads();
    if (tid < 128) {
        atomicAdd(&statsOut[tid], sStat[tid]);
    }
}

// ---------------------------------------------------------------- layer 3
// Wave-autonomous: per-wave xT [16k][32rows]; sW per 32-k half (barriers only
// there, 3 total); 4 self-paced 16-k phases; split column tile.
__global__ __launch_bounds__(256) void ssaLayer3Kernel(
    const float4* z2, const float4* wT3f4, const float* bias3,
    const float* gamma2, const float* beta2, const float* statsIn,
    float* poolMax, float* statsOut)
{
    __shared__ __align__(16) float sW[32 * 128];    // 16 KB (one 32-k half)
    __shared__ __align__(16) float xT[4][16 * 32];  //  8 KB, wave-private
    __shared__ float sB[128];
    __shared__ float sG[64];
    __shared__ float sH[64];
    __shared__ float sStat[256];
    int tid  = static_cast<int>(threadIdx.x);
    int R0   = static_cast<int>(blockIdx.x) * 128;
    int ty   = tid >> 4;
    int tx   = tid & 15;
    int wv   = tid >> 6;
    int lane = tid & 63;
    int lty  = ty & 3;
    int lr   = lane & 31;
    int hh   = lane >> 5;

    if (tid < 64) {
        double mean = static_cast<double>(statsIn[tid]) / static_cast<double>(kNRows);
        double var  = static_cast<double>(statsIn[64 + tid]) / static_cast<double>(kNRows) - mean * mean;
        double rstd = 1.0 / sqrt(var + 1e-5);
        float g = static_cast<float>(rstd) * gamma2[tid];
        sG[tid] = g;
        sH[tid] = beta2[tid] - static_cast<float>(mean) * g;
    }
    if (tid < 128) sB[tid] = bias3[tid];
    sStat[tid] = 0.0f;

    const float4* zrow = z2 + static_cast<size_t>(R0 + wv * 32 + lr) * 16;
    float* xw = xT[wv];
    float4* sWf4 = reinterpret_cast<float4*>(sW);

    float acc[8][8];

    #pragma unroll 1
    for (int half = 0; half < 2; half++) {
        if (half > 0) __syncthreads();
        #pragma unroll
        for (int q2 = 0; q2 < 4; q2++) {
            sWf4[q2 * 256 + tid] = wT3f4[half * 1024 + q2 * 256 + tid];
        }
        __syncthreads();
        if (half == 0) {
            #pragma unroll
            for (int i = 0; i < 8; i++) {
                #pragma unroll
                for (int j = 0; j < 4; j++) {
                    acc[i][j]     = sB[tx * 4 + j];
                    acc[i][4 + j] = sB[64 + tx * 4 + j];
                }
            }
        }

        #pragma unroll 1
        for (int sub = 0; sub < 2; sub++) {
            int pg = half * 2 + sub;
            // wave-local staging: 2 f4 per lane (2 lanes per row), no barrier
            #pragma unroll
            for (int m = 0; m < 2; m++) {
                float4 v = zrow[pg * 4 + hh * 2 + m];
                int kk = hh * 8 + m * 4;
                int kg = pg * 16 + kk;
                xw[(kk + 0) * 32 + lr] = fmaxf(v.x * sG[kg + 0] + sH[kg + 0], 0.0f);
                xw[(kk + 1) * 32 + lr] = fmaxf(v.y * sG[kg + 1] + sH[kg + 1], 0.0f);
                xw[(kk + 2) * 32 + lr] = fmaxf(v.z * sG[kg + 2] + sH[kg + 2], 0.0f);
                xw[(kk + 3) * 32 + lr] = fmaxf(v.w * sG[kg + 3] + sH[kg + 3], 0.0f);
            }

            for (int k = 0; k < 16; k++) {
                const float* xk = &xw[k * 32 + lty * 8];
                const float* wk = &sW[(sub * 16 + k) * 128];
                float wt[8];
                #pragma unroll
                for (int j = 0; j < 4; j++) wt[j] = wk[tx * 4 + j];
                #pragma unroll
                for (int j = 0; j < 4; j++) wt[4 + j] = wk[64 + tx * 4 + j];
                #pragma unroll
                for (int i = 0; i < 8; i++) {
                    float xv = xk[i];
                    #pragma unroll
                    for (int j = 0; j < 8; j++) {
                        acc[i][j] += xv * wt[j];
                    }
                }
            }
        }
    }

    // pooling (max over the wave's 32 rows) + stats
    int grp = static_cast<int>(blockIdx.x) * 4 + wv;
    float mx[8];
    float s[8];
    float q[8];
    #pragma unroll
    for (int j = 0; j < 8; j++) {
        mx[j] = acc[0][j];
        s[j]  = 0.0f;
        q[j]  = 0.0f;
    }
    #pragma unroll
    for (int i = 0; i < 8; i++)
        #pragma unroll
        for (int j = 0; j < 8; j++) {
            float v = acc[i][j];
            mx[j] = fmaxf(mx[j], v);
            s[j] += v;
            q[j] += v * v;
        }
    #pragma unroll
    for (int j = 0; j < 8; j++) {
        mx[j] = fmaxf(mx[j], __shfl_xor(mx[j], 16));
        mx[j] = fmaxf(mx[j], __shfl_xor(mx[j], 32));
        s[j] += __shfl_xor(s[j], 16); q[j] += __shfl_xor(q[j], 16);
        s[j] += __shfl_xor(s[j], 32); q[j] += __shfl_xor(q[j], 32);
    }
    if (lane < 16) {
        #pragma unroll
        for (int j = 0; j < 8; j++) {
            int c = (j < 4) ? (tx * 4 + j) : (64 + tx * 4 + (j - 4));
            poolMax[static_cast<size_t>(grp) * kC3 + c] = mx[j];
            atomicAdd(&sStat[c],       s[j]);
            atomicAdd(&sStat[128 + c], q[j]);
        }
    }
    __syncthreads();
    atomicAdd(&statsOut[tid], sStat[tid]);
}

// ---------------------------------------------------------------- finalize
__global__ __launch_bounds__(256) void ssaFinalKernel(
    const float* poolMax, const float* sum3, const float* sq3,
    const float* gamma3, const float* beta3, float* outTail)
{
    __shared__ float sG[128];
    __shared__ float sH[128];
    int tid = static_cast<int>(threadIdx.x);
    if (tid < 128) {
        double mean = static_cast<double>(sum3[tid]) / static_cast<double>(kNRows);
        double var  = static_cast<double>(sq3[tid]) / static_cast<double>(kNRows) - mean * mean;
        double rstd = 1.0 / sqrt(var + 1e-5);
        float g = static_cast<float>(rstd) * gamma3[tid];
        sG[tid] = g;
        sH[tid] = beta3[tid] - static_cast<float>(mean) * g;
    }
    __syncthreads();
    int e  = static_cast<int>(blockIdx.x) * 256 + tid;
    int b  = e >> 18;
    int ch = (e >> 11) & 127;
    int s  = e & 2047;
    size_t gi = static_cast<size_t>(b * kNS + s) * kC3 + ch;
    outTail[e] = fmaxf(poolMax[gi] * sG[ch] + sH[ch], 0.0f);
}

// ---------------------------------------------------------------- launch
static inline void* ssaWsAt(void* base, size_t byteOff)
{
    return static_cast<void*>(static_cast<char*>(base) + byteOff);
}

extern "C" __attribute__((visibility("default"), used))
void kernel_launch(void* const* d_in, const int* in_sizes, int n_in,
                   void* d_out, int out_size, void* d_ws, size_t ws_size,
                   hipStream_t stream)
{
    static_cast<void>(in_sizes);
    static_cast<void>(n_in);
    static_cast<void>(out_size);
    static_cast<void>(ws_size);

    const float*  xyz    = static_cast<const float*>(d_in[0]);
    const float4* points = static_cast<const float4*>(d_in[1]);
    const float*  newXyz = static_cast<const float*>(d_in[2]);
    const float*  w1Ptr  = static_cast<const float*>(d_in[3]);
    const float*  b1Ptr  = static_cast<const float*>(d_in[4]);
    const float*  g1Ptr  = static_cast<const float*>(d_in[5]);
    const float*  e1Ptr  = static_cast<const float*>(d_in[6]);
    const float*  w2Ptr  = static_cast<const float*>(d_in[7]);
    const float*  b2Ptr  = static_cast<const float*>(d_in[8]);
    const float*  g2Ptr  = static_cast<const float*>(d_in[9]);
    const float*  e2Ptr  = static_cast<const float*>(d_in[10]);
    const float*  w3Ptr  = static_cast<const float*>(d_in[11]);
    const float*  b3Ptr  = static_cast<const float*>(d_in[12]);
    const float*  g3Ptr  = static_cast<const float*>(d_in[13]);
    const float*  e3Ptr  = static_cast<const float*>(d_in[14]);

    float4* soa   = static_cast<float4*>(ssaWsAt(d_ws, 0));           //  1,048,576 B
    int*    bIdx  = static_cast<int*>(ssaWsAt(d_ws, 1048576));        //  1,048,576 B
    float4* bDxy  = static_cast<float4*>(ssaWsAt(d_ws, 2097152));     //  4,194,304 B
    float4* p1    = static_cast<float4*>(ssaWsAt(d_ws, 6291456));     // 16,777,216 B
    float4* z2    = static_cast<float4*>(ssaWsAt(d_ws, 23068672));    // 67,108,864 B
    float*  pMax  = static_cast<float*>(ssaWsAt(d_ws, 90177536));     //  4,194,304 B
    float*  stats = static_cast<float*>(ssaWsAt(d_ws, 94371840));     //      2,048 B
    float*  wT3   = static_cast<float*>(ssaWsAt(d_ws, 94373888));     //     32,768 B
    float*  wT2   = static_cast<float*>(ssaWsAt(d_ws, 94406656));     //     16,384 B
    float*  outF  = static_cast<float*>(d_out);

    ssaP1Kernel<<<kNPtsTot / 128, 256, 0, stream>>>(points, w1Ptr,
                                                    xyz, newXyz, w2Ptr, w3Ptr,
                                                    outF, soa, stats, wT2, wT3, p1);
    ssaBallKernel<<<kNGrp / 4, 256, 0, stream>>>(newXyz, soa, w1Ptr, b1Ptr,
                                                 reinterpret_cast<const float*>(p1),
                                                 bIdx, bDxy, stats);
    ssaLayer2Kernel<<<kNRows / 128, 256, 0, stream>>>(p1, w1Ptr, b1Ptr,
                                                      reinterpret_cast<const float4*>(wT2),
                                                      b2Ptr, g1Ptr, e1Ptr, stats, bIdx, bDxy,
                                                      z2, stats + 128);
    ssaLayer3Kernel<<<kNRows / 128, 256, 0, stream>>>(z2,
                                                      reinterpret_cast<const float4*>(wT3),
                                                      b3Ptr, g2Ptr, e2Ptr,
                                                      stats + 128, pMax, stats + 256);
    ssaFinalKernel<<<kNB * kC3 * kNS / 256, 256, 0, stream>>>(pMax, stats + 256, stats + 384,
                                                              g3Ptr, e3Ptr,
                                                              outF + kNB * kNS * 3);
}

// Round 15
// 304.827 us; speedup vs baseline: 1.0037x; 1.0037x over previous
//
#include <hip/hip_runtime.h>

// SingleScaleSA: B=4, N=16384, S=2048, K=32, mlp 64 -> 64 -> 128, radius 0.2.
// Round 37: r36's f32 ball distance REVERTED (FAILED absmax 0.88 -- selection
// set is defined by the reference's own expression; f64 resolves borderline
// memberships the same way, f32 reassociation flips them). Ball = r35's f64
// batch-8 scan byte-identical. L3 keeps the lane-paired staging from r36
// (value-identical, unmeasured until now). L2/P1/final unchanged.
constexpr int kNB      = 4;
constexpr int kNPts    = 16384;
constexpr int kNS      = 2048;
constexpr int kNK      = 32;
constexpr int kC3      = 128;
constexpr int kNRows   = kNB * kNS * kNK;   // 262144
constexpr int kNGrp    = kNB * kNS;         // 8192
constexpr int kNPtsTot = kNB * kNPts;       // 65536
constexpr double kR2   = 0.2 * 0.2;

// ---------------------------------------------------------------- P1 GEMM (+prep)
__global__ __launch_bounds__(256) void ssaP1Kernel(
    const float4* points, const float* w1,
    const float* xyz, const float* newXyz, const float* w2, const float* w3,
    float* outHead, float4* soa, float* stats, float* wT2, float* wT3,
    float4* p1)
{
    __shared__ float xT[32 * 128];
    __shared__ float sW[64 * 64];
    int tid = static_cast<int>(threadIdx.x);
    int R0  = static_cast<int>(blockIdx.x) * 128;
    int ty  = tid >> 4;
    int tx  = tid & 15;
    int r   = tid & 127;
    int h   = tid >> 7;

    // ---- merged prep (blocks 0..255 cover all ranges)
    int t = static_cast<int>(blockIdx.x) * 256 + tid;
    if (t < kNPtsTot) {
        soa[t] = make_float4(xyz[t * 3 + 0], xyz[t * 3 + 1], xyz[t * 3 + 2], 0.0f);
    }
    if (t < kNB * kNS * 3) {
        outHead[t] = newXyz[t];
    }
    if (t < 512) {
        stats[t] = 0.0f;
    }
    if (t < 64 * 128) {
        int k = t >> 7;
        int c = t & 127;
        wT3[t] = w3[c * 64 + k];
    }
    if (t < 64 * 64) {
        int k = t >> 6;
        int c = t & 63;
        wT2[t] = w2[c * 64 + k];
    }

    for (int i = tid; i < 64 * 64; i += 256) {
        int k = i >> 6;
        int c = i & 63;
        sW[i] = w1[c * 67 + 3 + k];
    }
    __syncthreads();

    float acc[8][4];
    #pragma unroll
    for (int i = 0; i < 8; i++)
        #pragma unroll
        for (int j = 0; j < 4; j++) acc[i][j] = 0.0f;

    const float4* prow = points + static_cast<size_t>(R0 + r) * 16;

    #pragma unroll 1
    for (int ch = 0; ch < 2; ch++) {
        if (ch > 0) __syncthreads();
        for (int j = h * 4; j < h * 4 + 4; j++) {
            float4 v = prow[ch * 8 + j];
            int k = j * 4;
            xT[(k + 0) * 128 + r] = v.x;
            xT[(k + 1) * 128 + r] = v.y;
            xT[(k + 2) * 128 + r] = v.z;
            xT[(k + 3) * 128 + r] = v.w;
        }
        __syncthreads();

        int kw = ch * 32;
        for (int k = 0; k < 32; k++) {
            const float* xk = &xT[k * 128 + ty * 8];
            const float* wk = &sW[(kw + k) * 64 + tx * 4];
            float w0 = wk[0], w1v = wk[1], w2v = wk[2], w3v = wk[3];
            #pragma unroll
            for (int i = 0; i < 8; i++) {
                float xv = xk[i];
                acc[i][0] += xv * w0;
                acc[i][1] += xv * w1v;
                acc[i][2] += xv * w2v;
                acc[i][3] += xv * w3v;
            }
        }
    }

    #pragma unroll
    for (int i = 0; i < 8; i++) {
        p1[static_cast<size_t>(R0 + ty * 8 + i) * 16 + tx] =
            make_float4(acc[i][0], acc[i][1], acc[i][2], acc[i][3]);
    }
}

// ---------------------------------------------------------------- ball query + BN1 stats
__global__ __launch_bounds__(256) void ssaBallKernel(
    const float* newXyz, const float4* soa, const float* w1, const float* bias1,
    const float* p1f, int* ballIdx, float4* ballDxyz, float* stats)
{
    __shared__ int   sIdx[4][32];
    __shared__ float sDx[4][32];
    __shared__ float sDy[4][32];
    __shared__ float sDz[4][32];
    __shared__ float sStat[128];
    int tid  = static_cast<int>(threadIdx.x);
    int wv   = tid >> 6;
    int lane = tid & 63;
    int w    = static_cast<int>(blockIdx.x) * 4 + wv;
    int b    = w >> 11;
    if (tid < 128) sStat[tid] = 0.0f;
    __syncthreads();

    float qx = newXyz[w * 3 + 0];
    float qy = newXyz[w * 3 + 1];
    float qz = newXyz[w * 3 + 2];
    double qxd = static_cast<double>(qx);
    double qyd = static_cast<double>(qy);
    double qzd = static_cast<double>(qz);
    double qq  = qxd * qxd + qyd * qyd + qzd * qzd;
    const float4* sp = soa + b * kNPts;
    int*    oi = ballIdx  + static_cast<size_t>(w) * kNK;
    float4* od = ballDxyz + static_cast<size_t>(w) * kNK;

    int cnt = 0;
    int firstN = -1;
    float fdx = 0.0f, fdy = 0.0f, fdz = 0.0f;

    // batched scan: 8 chunks (512 points) per iteration; loads issued upfront.
    for (int base = 0; base < kNPts && cnt < kNK; base += 512) {
        float4 pA = sp[base +   0 + lane];
        float4 pB = sp[base +  64 + lane];
        float4 pC = sp[base + 128 + lane];
        float4 pD = sp[base + 192 + lane];
        float4 pE = sp[base + 256 + lane];
        float4 pF = sp[base + 320 + lane];
        float4 pG = sp[base + 384 + lane];
        float4 pH = sp[base + 448 + lane];
        #pragma unroll
        for (int c = 0; c < 8; c++) {
            if (cnt >= kNK) break;
            float4 p = (c == 0) ? pA : (c == 1) ? pB : (c == 2) ? pC : (c == 3) ? pD
                     : (c == 4) ? pE : (c == 5) ? pF : (c == 6) ? pG : pH;
            int cbase = base + c * 64;
            double pxd = static_cast<double>(p.x);
            double pyd = static_cast<double>(p.y);
            double pzd = static_cast<double>(p.z);
            double d2  = qq + (pxd * pxd + pyd * pyd + pzd * pzd)
                       - 2.0 * (qxd * pxd + qyd * pyd + qzd * pzd);
            bool hit   = (d2 <= kR2);
            unsigned long long m = __ballot(hit);
            int pos = cnt + __popcll(m & ((1ull << lane) - 1ull));
            if (hit && pos < kNK) {
                float dx = p.x - qx;
                float dy = p.y - qy;
                float dz = p.z - qz;
                oi[pos] = cbase + lane;
                od[pos] = make_float4(dx, dy, dz, 0.0f);
                sIdx[wv][pos] = cbase + lane;
                sDx[wv][pos] = dx;
                sDy[wv][pos] = dy;
                sDz[wv][pos] = dz;
                if (pos == 0) { firstN = cbase + lane; fdx = dx; fdy = dy; fdz = dz; }
            }
            cnt += __popcll(m);
        }
    }
    if (cnt < kNK) {
        unsigned long long hv = __ballot(firstN >= 0);
        int fi;
        float dx, dy, dz;
        if (hv != 0ull) {
            int src = __builtin_ctzll(hv);
            fi = __shfl(firstN, src);
            dx = __shfl(fdx, src);
            dy = __shfl(fdy, src);
            dz = __shfl(fdz, src);
        } else {
            float4 p = sp[kNPts - 1];
            fi = kNPts - 1;
            dx = p.x - qx;
            dy = p.y - qy;
            dz = p.z - qz;
        }
        for (int p2 = cnt + lane; p2 < kNK; p2 += 64) {
            oi[p2] = fi;
            od[p2] = make_float4(dx, dy, dz, 0.0f);
            sIdx[wv][p2] = fi;
            sDx[wv][p2] = dx;
            sDy[wv][p2] = dy;
            sDz[wv][p2] = dz;
        }
    }

    // BN1 stats: lane = channel; z1 = P1[gi,c] + dxyz.W1xyz[:,c] + b1[c].
    float wa  = w1[lane * 67 + 0];
    float wbv = w1[lane * 67 + 1];
    float wc  = w1[lane * 67 + 2];
    float bb  = bias1[lane];
    const float* pb = p1f + static_cast<size_t>(b) * kNPts * 64;
    float s = 0.0f, q = 0.0f;
    #pragma unroll 8
    for (int k2 = 0; k2 < kNK; k2++) {
        int g = sIdx[wv][k2];
        float val = pb[static_cast<size_t>(g) * 64 + lane]
                  + sDx[wv][k2] * wa + sDy[wv][k2] * wbv + sDz[wv][k2] * wc + bb;
        s += val;
        q += val * val;
    }
    atomicAdd(&sStat[lane], s);
    atomicAdd(&sStat[64 + lane], q);
    __syncthreads();
    if (tid < 128) {
        atomicAdd(&stats[tid], sStat[tid]);
    }
}

// ---------------------------------------------------------------- layer 2
// Single-phase wave-autonomous: full W2 in LDS (staged once); each wave
// gathers its 32 rows' full 128 B in one 8-load burst; 64-k FMA runs with
// zero mid-kernel barriers. relu(bn1(P1[gi] + dxyz@W1xyz + b1)) @ W2.
__global__ __launch_bounds__(256) void ssaLayer2Kernel(
    const float4* p1, const float* w1, const float* bias1,
    const float4* wT2f4, const float* bias2,
    const float* gamma1, const float* beta1, const float* statsIn,
    const int* ballIdx, const float4* ballDxyz,
    float4* z2, float* statsOut)
{
    __shared__ __align__(16) float sW[64 * 64];     // 16 KB (full W2^T)
    __shared__ __align__(16) float xT[4][64 * 32];  // 32 KB, wave-private
    __shared__ float sWx[256];
    __shared__ float sB[64];
    __shared__ float sG[64];
    __shared__ float sH[64];
    __shared__ float sStat[128];
    int tid  = static_cast<int>(threadIdx.x);
    int R0   = static_cast<int>(blockIdx.x) * 128;
    int ty   = tid >> 4;
    int tx   = tid & 15;
    int wv   = tid >> 6;
    int lane = tid & 63;
    int lty  = ty & 3;
    int lr   = lane & 31;
    int hh   = lane >> 5;

    if (tid < 64) {
        sB[tid] = bias2[tid];
        double mean = static_cast<double>(statsIn[tid]) / static_cast<double>(kNRows);
        double var  = static_cast<double>(statsIn[64 + tid]) / static_cast<double>(kNRows) - mean * mean;
        double rstd = 1.0 / sqrt(var + 1e-5);
        float g = static_cast<float>(rstd) * gamma1[tid];
        sG[tid] = g;
        sH[tid] = beta1[tid] - static_cast<float>(mean) * g;
        sWx[tid]       = w1[tid * 67 + 0];
        sWx[64 + tid]  = w1[tid * 67 + 1];
        sWx[128 + tid] = w1[tid * 67 + 2];
        sWx[192 + tid] = bias1[tid];
    }
    if (tid < 128) sStat[tid] = 0.0f;

    int grow = R0 + wv * 32 + lr;
    int gi = ballIdx[grow];
    float4 dd = ballDxyz[grow];
    int b = R0 >> 16;
    const float4* prow = p1 + (static_cast<size_t>(b) * kNPts + static_cast<size_t>(gi)) * 16;
    float dx = dd.x, dy = dd.y, dz = dd.z;
    float* xw = xT[wv];

    // full W2 -> LDS once (coalesced f4)
    float4* sWf4 = reinterpret_cast<float4*>(sW);
    #pragma unroll
    for (int q2 = 0; q2 < 4; q2++) {
        sWf4[q2 * 256 + tid] = wT2f4[q2 * 256 + tid];
    }
    __syncthreads();   // covers sW + sG/sH/sWx before staging reads

    // wave-local staging: 8 f4 per lane (2 lanes per row), single exposure
    #pragma unroll
    for (int m = 0; m < 8; m++) {
        float4 v = prow[hh * 8 + m];
        int kk = hh * 32 + m * 4;
        float z0  = v.x + dx * sWx[kk + 0] + dy * sWx[64 + kk + 0] + dz * sWx[128 + kk + 0] + sWx[192 + kk + 0];
        float z1v = v.y + dx * sWx[kk + 1] + dy * sWx[64 + kk + 1] + dz * sWx[128 + kk + 1] + sWx[192 + kk + 1];
        float z2v = v.z + dx * sWx[kk + 2] + dy * sWx[64 + kk + 2] + dz * sWx[128 + kk + 2] + sWx[192 + kk + 2];
        float z3v = v.w + dx * sWx[kk + 3] + dy * sWx[64 + kk + 3] + dz * sWx[128 + kk + 3] + sWx[192 + kk + 3];
        xw[(kk + 0) * 32 + lr] = fmaxf(z0  * sG[kk + 0] + sH[kk + 0], 0.0f);
        xw[(kk + 1) * 32 + lr] = fmaxf(z1v * sG[kk + 1] + sH[kk + 1], 0.0f);
        xw[(kk + 2) * 32 + lr] = fmaxf(z2v * sG[kk + 2] + sH[kk + 2], 0.0f);
        xw[(kk + 3) * 32 + lr] = fmaxf(z3v * sG[kk + 3] + sH[kk + 3], 0.0f);
    }

    float acc[8][4];
    #pragma unroll
    for (int i = 0; i < 8; i++)
        #pragma unroll
        for (int j = 0; j < 4; j++) acc[i][j] = sB[tx * 4 + j];

    for (int k = 0; k < 64; k++) {
        const float* xk = &xw[k * 32 + lty * 8];
        const float* wk = &sW[k * 64 + tx * 4];
        float w0 = wk[0], w1v = wk[1], w2v = wk[2], w3v = wk[3];
        #pragma unroll
        for (int i = 0; i < 8; i++) {
            float xv = xk[i];
            acc[i][0] += xv * w0;
            acc[i][1] += xv * w1v;
            acc[i][2] += xv * w2v;
            acc[i][3] += xv * w3v;
        }
    }

    float s[4] = {0.f, 0.f, 0.f, 0.f};
    float q[4] = {0.f, 0.f, 0.f, 0.f};
    #pragma unroll
    for (int i = 0; i < 8; i++) {
        int row = R0 + ty * 8 + i;
        z2[static_cast<size_t>(row) * 16 + tx] =
            make_float4(acc[i][0], acc[i][1], acc[i][2], acc[i][3]);
        #pragma unroll
        for (int j = 0; j < 4; j++) {
            s[j] += acc[i][j];
            q[j] += acc[i][j] * acc[i][j];
        }
    }
    #pragma unroll
    for (int j = 0; j < 4; j++) {
        s[j] += __shfl_xor(s[j], 16); q[j] += __shfl_xor(q[j], 16);
        s[j] += __shfl_xor(s[j], 32); q[j] += __shfl_xor(q[j], 32);
    }
    if (lane < 16) {
        #pragma unroll
        for (int j = 0; j < 4; j++) {
            atomicAdd(&sStat[tx * 4 + j],      s[j]);
            atomicAdd(&sStat[64 + tx * 4 + j], q[j]);
        }
    }
    __syncthreads();
    if (tid < 128) {
        atomicAdd(&statsOut[tid], sStat[tid]);
    }
}

// ---------------------------------------------------------------- layer 3
// Wave-autonomous: per-wave xT [16k][32rows]; sW per 32-k half (barriers only
// there, 3 total); 4 self-paced 16-k phases; split column tile. z2 staging
// lane-paired (row=lane>>1, colpair=lane&1) for 32B-coalesced reads.
__global__ __launch_bounds__(256) void ssaLayer3Kernel(
    const float4* z2, const float4* wT3f4, const float* bias3,
    const float* gamma2, const float* beta2, const float* statsIn,
    float* poolMax, float* statsOut)
{
    __shared__ __align__(16) float sW[32 * 128];    // 16 KB (one 32-k half)
    __shared__ __align__(16) float xT[4][16 * 32];  //  8 KB, wave-private
    __shared__ float sB[128];
    __shared__ float sG[64];
    __shared__ float sH[64];
    __shared__ float sStat[256];
    int tid  = static_cast<int>(threadIdx.x);
    int R0   = static_cast<int>(blockIdx.x) * 128;
    int ty   = tid >> 4;
    int tx   = tid & 15;
    int wv   = tid >> 6;
    int lane = tid & 63;
    int lty  = ty & 3;
    int lr2  = lane >> 1;   // staging row (0..31)
    int c2   = lane & 1;    // staging col-pair

    if (tid < 64) {
        double mean = static_cast<double>(statsIn[tid]) / static_cast<double>(kNRows);
        double var  = static_cast<double>(statsIn[64 + tid]) / static_cast<double>(kNRows) - mean * mean;
        double rstd = 1.0 / sqrt(var + 1e-5);
        float g = static_cast<float>(rstd) * gamma2[tid];
        sG[tid] = g;
        sH[tid] = beta2[tid] - static_cast<float>(mean) * g;
    }
    if (tid < 128) sB[tid] = bias3[tid];
    sStat[tid] = 0.0f;

    const float4* zrow = z2 + static_cast<size_t>(R0 + wv * 32 + lr2) * 16;
    float* xw = xT[wv];
    float4* sWf4 = reinterpret_cast<float4*>(sW);

    float acc[8][8];

    #pragma unroll 1
    for (int half = 0; half < 2; half++) {
        if (half > 0) __syncthreads();
        #pragma unroll
        for (int q2 = 0; q2 < 4; q2++) {
            sWf4[q2 * 256 + tid] = wT3f4[half * 1024 + q2 * 256 + tid];
        }
        __syncthreads();
        if (half == 0) {
            #pragma unroll
            for (int i = 0; i < 8; i++) {
                #pragma unroll
                for (int j = 0; j < 4; j++) {
                    acc[i][j]     = sB[tx * 4 + j];
                    acc[i][4 + j] = sB[64 + tx * 4 + j];
                }
            }
        }

        #pragma unroll 1
        for (int sub = 0; sub < 2; sub++) {
            int pg = half * 2 + sub;
            // wave-local staging: 2 f4 per lane, lane-paired coalescing
            #pragma unroll
            for (int m = 0; m < 2; m++) {
                float4 v = zrow[pg * 4 + c2 * 2 + m];
                int kk = (c2 * 2 + m) * 4;
                int kg = pg * 16 + kk;
                xw[(kk + 0) * 32 + lr2] = fmaxf(v.x * sG[kg + 0] + sH[kg + 0], 0.0f);
                xw[(kk + 1) * 32 + lr2] = fmaxf(v.y * sG[kg + 1] + sH[kg + 1], 0.0f);
                xw[(kk + 2) * 32 + lr2] = fmaxf(v.z * sG[kg + 2] + sH[kg + 2], 0.0f);
                xw[(kk + 3) * 32 + lr2] = fmaxf(v.w * sG[kg + 3] + sH[kg + 3], 0.0f);
            }

            for (int k = 0; k < 16; k++) {
                const float* xk = &xw[k * 32 + lty * 8];
                const float* wk = &sW[(sub * 16 + k) * 128];
                float wt[8];
                #pragma unroll
                for (int j = 0; j < 4; j++) wt[j] = wk[tx * 4 + j];
                #pragma unroll
                for (int j = 0; j < 4; j++) wt[4 + j] = wk[64 + tx * 4 + j];
                #pragma unroll
                for (int i = 0; i < 8; i++) {
                    float xv = xk[i];
                    #pragma unroll
                    for (int j = 0; j < 8; j++) {
                        acc[i][j] += xv * wt[j];
                    }
                }
            }
        }
    }

    // pooling (max over the wave's 32 rows) + stats
    int grp = static_cast<int>(blockIdx.x) * 4 + wv;
    float mx[8];
    float s[8];
    float q[8];
    #pragma unroll
    for (int j = 0; j < 8; j++) {
        mx[j] = acc[0][j];
        s[j]  = 0.0f;
        q[j]  = 0.0f;
    }
    #pragma unroll
    for (int i = 0; i < 8; i++)
        #pragma unroll
        for (int j = 0; j < 8; j++) {
            float v = acc[i][j];
            mx[j] = fmaxf(mx[j], v);
            s[j] += v;
            q[j] += v * v;
        }
    #pragma unroll
    for (int j = 0; j < 8; j++) {
        mx[j] = fmaxf(mx[j], __shfl_xor(mx[j], 16));
        mx[j] = fmaxf(mx[j], __shfl_xor(mx[j], 32));
        s[j] += __shfl_xor(s[j], 16); q[j] += __shfl_xor(q[j], 16);
        s[j] += __shfl_xor(s[j], 32); q[j] += __shfl_xor(q[j], 32);
    }
    int lane2 = tid & 63;
    if (lane2 < 16) {
        #pragma unroll
        for (int j = 0; j < 8; j++) {
            int c = (j < 4) ? (tx * 4 + j) : (64 + tx * 4 + (j - 4));
            poolMax[static_cast<size_t>(grp) * kC3 + c] = mx[j];
            atomicAdd(&sStat[c],       s[j]);
            atomicAdd(&sStat[128 + c], q[j]);
        }
    }
    __syncthreads();
    atomicAdd(&statsOut[tid], sStat[tid]);
}

// ---------------------------------------------------------------- finalize
__global__ __launch_bounds__(256) void ssaFinalKernel(
    const float* poolMax, const float* sum3, const float* sq3,
    const float* gamma3, const float* beta3, float* outTail)
{
    __shared__ float sG[128];
    __shared__ float sH[128];
    int tid = static_cast<int>(threadIdx.x);
    if (tid < 128) {
        double mean = static_cast<double>(sum3[tid]) / static_cast<double>(kNRows);
        double var  = static_cast<double>(sq3[tid]) / static_cast<double>(kNRows) - mean * mean;
        double rstd = 1.0 / sqrt(var + 1e-5);
        float g = static_cast<float>(rstd) * gamma3[tid];
        sG[tid] = g;
        sH[tid] = beta3[tid] - static_cast<float>(mean) * g;
    }
    __syncthreads();
    int e  = static_cast<int>(blockIdx.x) * 256 + tid;
    int b  = e >> 18;
    int ch = (e >> 11) & 127;
    int s  = e & 2047;
    size_t gi = static_cast<size_t>(b * kNS + s) * kC3 + ch;
    outTail[e] = fmaxf(poolMax[gi] * sG[ch] + sH[ch], 0.0f);
}

// ---------------------------------------------------------------- launch
static inline void* ssaWsAt(void* base, size_t byteOff)
{
    return static_cast<void*>(static_cast<char*>(base) + byteOff);
}

extern "C" __attribute__((visibility("default"), used))
void kernel_launch(void* const* d_in, const int* in_sizes, int n_in,
                   void* d_out, int out_size, void* d_ws, size_t ws_size,
                   hipStream_t stream)
{
    static_cast<void>(in_sizes);
    static_cast<void>(n_in);
    static_cast<void>(out_size);
    static_cast<void>(ws_size);

    const float*  xyz    = static_cast<const float*>(d_in[0]);
    const float4* points = static_cast<const float4*>(d_in[1]);
    const float*  newXyz = static_cast<const float*>(d_in[2]);
    const float*  w1Ptr  = static_cast<const float*>(d_in[3]);
    const float*  b1Ptr  = static_cast<const float*>(d_in[4]);
    const float*  g1Ptr  = static_cast<const float*>(d_in[5]);
    const float*  e1Ptr  = static_cast<const float*>(d_in[6]);
    const float*  w2Ptr  = static_cast<const float*>(d_in[7]);
    const float*  b2Ptr  = static_cast<const float*>(d_in[8]);
    const float*  g2Ptr  = static_cast<const float*>(d_in[9]);
    const float*  e2Ptr  = static_cast<const float*>(d_in[10]);
    const float*  w3Ptr  = static_cast<const float*>(d_in[11]);
    const float*  b3Ptr  = static_cast<const float*>(d_in[12]);
    const float*  g3Ptr  = static_cast<const float*>(d_in[13]);
    const float*  e3Ptr  = static_cast<const float*>(d_in[14]);

    float4* soa   = static_cast<float4*>(ssaWsAt(d_ws, 0));           //  1,048,576 B
    int*    bIdx  = static_cast<int*>(ssaWsAt(d_ws, 1048576));        //  1,048,576 B
    float4* bDxy  = static_cast<float4*>(ssaWsAt(d_ws, 2097152));     //  4,194,304 B
    float4* p1    = static_cast<float4*>(ssaWsAt(d_ws, 6291456));     // 16,777,216 B
    float4* z2    = static_cast<float4*>(ssaWsAt(d_ws, 23068672));    // 67,108,864 B
    float*  pMax  = static_cast<float*>(ssaWsAt(d_ws, 90177536));     //  4,194,304 B
    float*  stats = static_cast<float*>(ssaWsAt(d_ws, 94371840));     //      2,048 B
    float*  wT3   = static_cast<float*>(ssaWsAt(d_ws, 94373888));     //     32,768 B
    float*  wT2   = static_cast<float*>(ssaWsAt(d_ws, 94406656));     //     16,384 B
    float*  outF  = static_cast<float*>(d_out);

    ssaP1Kernel<<<kNPtsTot / 128, 256, 0, stream>>>(points, w1Ptr,
                                                    xyz, newXyz, w2Ptr, w3Ptr,
                                                    outF, soa, stats, wT2, wT3, p1);
    ssaBallKernel<<<kNGrp / 4, 256, 0, stream>>>(newXyz, soa, w1Ptr, b1Ptr,
                                                 reinterpret_cast<const float*>(p1),
                                                 bIdx, bDxy, stats);
    ssaLayer2Kernel<<<kNRows / 128, 256, 0, stream>>>(p1, w1Ptr, b1Ptr,
                                                      reinterpret_cast<const float4*>(wT2),
                                                      b2Ptr, g1Ptr, e1Ptr, stats, bIdx, bDxy,
                                                      z2, stats + 128);
    ssaLayer3Kernel<<<kNRows / 128, 256, 0, stream>>>(z2,
                                                      reinterpret_cast<const float4*>(wT3),
                                                      b3Ptr, g2Ptr, e2Ptr,
                                                      stats + 128, pMax, stats + 256);
    ssaFinalKernel<<<kNB * kC3 * kNS / 256, 256, 0, stream>>>(pMax, stats + 256, stats + 384,
                                                              g3Ptr, e3Ptr,
                                                              outF + kNB * kNS * 3);
}